// Round 8
// baseline (159.779 us; speedup 1.0000x reference)
//
#include <hip/hip_runtime.h>
#include <hip/hip_bf16.h>

#define C 64

// bf16 helpers (manual RNE pack / cheap unpack)
__device__ __forceinline__ float bflo(unsigned u) { return __uint_as_float(u << 16); }
__device__ __forceinline__ float bfhi(unsigned u) { return __uint_as_float(u & 0xffff0000u); }
__device__ __forceinline__ unsigned bfrne(float f) {
    unsigned u = __float_as_uint(f);
    return (u + 0x7fffu + ((u >> 16) & 1u)) >> 16;
}

// ---- count in-degree over dst; atomic return = rank of edge within its bucket ----
__global__ void count_deg_kernel(const int* __restrict__ dst, unsigned* __restrict__ deg,
                                 unsigned* __restrict__ rank, int E) {
    int e = blockIdx.x * blockDim.x + threadIdx.x;
    if (e < E) {
        rank[e] = atomicAdd(&deg[dst[e]], 1u);
    }
}

// ---- exclusive scan level 1 (1024/block) + dis = rsqrt(deg+1) fused ----
__global__ void scan1_kernel(const unsigned* __restrict__ deg, unsigned* __restrict__ offs,
                             unsigned* __restrict__ bsum, float* __restrict__ dis, int n) {
    __shared__ unsigned s[256];
    int t = threadIdx.x;
    int base = blockIdx.x * 1024 + t * 4;
    unsigned v0 = 0, v1 = 0, v2 = 0, v3 = 0;
    if (base + 0 < n) v0 = deg[base + 0];
    if (base + 1 < n) v1 = deg[base + 1];
    if (base + 2 < n) v2 = deg[base + 2];
    if (base + 3 < n) v3 = deg[base + 3];
    if (base + 0 < n) dis[base + 0] = rsqrtf((float)(v0 + 1u));
    if (base + 1 < n) dis[base + 1] = rsqrtf((float)(v1 + 1u));
    if (base + 2 < n) dis[base + 2] = rsqrtf((float)(v2 + 1u));
    if (base + 3 < n) dis[base + 3] = rsqrtf((float)(v3 + 1u));
    s[t] = v0 + v1 + v2 + v3;
    __syncthreads();
    for (int d = 1; d < 256; d <<= 1) {
        unsigned val = (t >= d) ? s[t - d] : 0u;
        __syncthreads();
        s[t] += val;
        __syncthreads();
    }
    unsigned excl = (t == 0) ? 0u : s[t - 1];
    if (t == 255) bsum[blockIdx.x] = s[255];
    if (base + 0 < n) offs[base + 0] = excl;
    if (base + 1 < n) offs[base + 1] = excl + v0;
    if (base + 2 < n) offs[base + 2] = excl + v0 + v1;
    if (base + 3 < n) offs[base + 3] = excl + v0 + v1 + v2;
}

// ---- scan block sums (single block; nb <= 256) ----
__global__ void scan2_kernel(unsigned* __restrict__ bsum, int nb) {
    __shared__ unsigned s[256];
    int t = threadIdx.x;
    s[t] = (t < nb) ? bsum[t] : 0u;
    __syncthreads();
    for (int d = 1; d < 256; d <<= 1) {
        unsigned val = (t >= d) ? s[t - d] : 0u;
        __syncthreads();
        s[t] += val;
        __syncthreads();
    }
    if (t < nb) bsum[t] = (t == 0) ? 0u : s[t - 1];
}

// ---- bucket edges by dst using precomputed rank (no atomics) ----
__global__ void bucket_kernel(const int* __restrict__ src, const int* __restrict__ dst,
                              const unsigned* __restrict__ offs, const unsigned* __restrict__ bsum,
                              const unsigned* __restrict__ rank, unsigned* __restrict__ ssrc, int E) {
    int e = blockIdx.x * blockDim.x + threadIdx.x;
    if (e < E) {
        int d = dst[e];
        unsigned pos = offs[d] + bsum[d >> 10] + rank[e];
        ssrc[pos] = (unsigned)src[e];
    }
}

// ---- hs(bf16) = dis[row] * (x @ W): LDS-tiled, 4x4 register micro-tile ----
__global__ void __launch_bounds__(256)
gemm64_kernel(const float* __restrict__ x, const float* __restrict__ W,
              const float* __restrict__ dis, unsigned short* __restrict__ hsb, int n) {
    __shared__ float Xl[64][68];
    __shared__ float Wl[64][64];
    int tid = threadIdx.x;
    int rbase = blockIdx.x * 64;
    for (int i = tid; i < 1024; i += 256) {
        ((float4*)Wl)[i] = ((const float4*)W)[i];
    }
    for (int i = tid; i < 1024; i += 256) {
        int r = i >> 4, kq = i & 15;
        float4 v;
        if (rbase + r < n) v = ((const float4*)(x + (size_t)(rbase + r) * C))[kq];
        else               v = make_float4(0.f, 0.f, 0.f, 0.f);
        *(float4*)&Xl[r][kq * 4] = v;
    }
    __syncthreads();

    int tx = tid & 15;      // channel group: channels 4tx..4tx+3
    int ty = tid >> 4;      // row group: rows 4ty..4ty+3
    float4 acc[4];
    #pragma unroll
    for (int j = 0; j < 4; ++j) acc[j] = make_float4(0.f, 0.f, 0.f, 0.f);

    for (int kb = 0; kb < 16; ++kb) {
        float4 wv0 = *(const float4*)&Wl[kb * 4 + 0][tx * 4];
        float4 wv1 = *(const float4*)&Wl[kb * 4 + 1][tx * 4];
        float4 wv2 = *(const float4*)&Wl[kb * 4 + 2][tx * 4];
        float4 wv3 = *(const float4*)&Wl[kb * 4 + 3][tx * 4];
        #pragma unroll
        for (int j = 0; j < 4; ++j) {
            float4 xv = *(const float4*)&Xl[ty * 4 + j][kb * 4];
            acc[j].x = fmaf(xv.x, wv0.x, acc[j].x);
            acc[j].y = fmaf(xv.x, wv0.y, acc[j].y);
            acc[j].z = fmaf(xv.x, wv0.z, acc[j].z);
            acc[j].w = fmaf(xv.x, wv0.w, acc[j].w);
            acc[j].x = fmaf(xv.y, wv1.x, acc[j].x);
            acc[j].y = fmaf(xv.y, wv1.y, acc[j].y);
            acc[j].z = fmaf(xv.y, wv1.z, acc[j].z);
            acc[j].w = fmaf(xv.y, wv1.w, acc[j].w);
            acc[j].x = fmaf(xv.z, wv2.x, acc[j].x);
            acc[j].y = fmaf(xv.z, wv2.y, acc[j].y);
            acc[j].z = fmaf(xv.z, wv2.z, acc[j].z);
            acc[j].w = fmaf(xv.z, wv2.w, acc[j].w);
            acc[j].x = fmaf(xv.w, wv3.x, acc[j].x);
            acc[j].y = fmaf(xv.w, wv3.y, acc[j].y);
            acc[j].z = fmaf(xv.w, wv3.z, acc[j].z);
            acc[j].w = fmaf(xv.w, wv3.w, acc[j].w);
        }
    }
    #pragma unroll
    for (int j = 0; j < 4; ++j) {
        int row = rbase + ty * 4 + j;
        if (row < n) {
            float d = dis[row];
            unsigned p0 = bfrne(acc[j].x * d) | (bfrne(acc[j].y * d) << 16);
            unsigned p1 = bfrne(acc[j].z * d) | (bfrne(acc[j].w * d) << 16);
            ((uint2*)(hsb + (size_t)row * C))[tx] = make_uint2(p0, p1);
        }
    }
}

// ---- gather: one wave per node; 8 edge-groups x 8 lanes (uint4 = 8 bf16 each) ----
__global__ void gather_kernel(const unsigned* __restrict__ offs, const unsigned* __restrict__ bsum,
                              const unsigned* __restrict__ deg, const unsigned* __restrict__ ssrc,
                              const float* __restrict__ dis, const unsigned short* __restrict__ hsb,
                              const float* __restrict__ b, float* __restrict__ out, int n) {
    int node = blockIdx.x * 4 + (threadIdx.x >> 6);
    if (node >= n) return;
    int lane = threadIdx.x & 63;
    int g = lane >> 3;          // edge group 0..7
    int l = lane & 7;           // uint4 slot within 128B row (channels 8l..8l+7)
    unsigned off = offs[node] + bsum[node >> 10];
    unsigned dg  = deg[node];
    float a0 = 0.f, a1 = 0.f, a2 = 0.f, a3 = 0.f, a4 = 0.f, a5 = 0.f, a6 = 0.f, a7 = 0.f;
    unsigned k = 0;
    for (; k + 16 <= dg; k += 16) {
        unsigned s0 = ssrc[off + k + g];
        unsigned s1 = ssrc[off + k + 8 + g];
        uint4 v0 = ((const uint4*)(hsb + (size_t)s0 * C))[l];
        uint4 v1 = ((const uint4*)(hsb + (size_t)s1 * C))[l];
        a0 += bflo(v0.x) + bflo(v1.x); a1 += bfhi(v0.x) + bfhi(v1.x);
        a2 += bflo(v0.y) + bflo(v1.y); a3 += bfhi(v0.y) + bfhi(v1.y);
        a4 += bflo(v0.z) + bflo(v1.z); a5 += bfhi(v0.z) + bfhi(v1.z);
        a6 += bflo(v0.w) + bflo(v1.w); a7 += bfhi(v0.w) + bfhi(v1.w);
    }
    if (k + 8 <= dg) {
        unsigned s0 = ssrc[off + k + g];
        uint4 v0 = ((const uint4*)(hsb + (size_t)s0 * C))[l];
        a0 += bflo(v0.x); a1 += bfhi(v0.x);
        a2 += bflo(v0.y); a3 += bfhi(v0.y);
        a4 += bflo(v0.z); a5 += bfhi(v0.z);
        a6 += bflo(v0.w); a7 += bfhi(v0.w);
        k += 8;
    }
    if (k + g < dg) {
        unsigned s0 = ssrc[off + k + g];
        uint4 v0 = ((const uint4*)(hsb + (size_t)s0 * C))[l];
        a0 += bflo(v0.x); a1 += bfhi(v0.x);
        a2 += bflo(v0.y); a3 += bfhi(v0.y);
        a4 += bflo(v0.z); a5 += bfhi(v0.z);
        a6 += bflo(v0.w); a7 += bfhi(v0.w);
    }
    // reduce across the 8 edge groups (xor 8, 16, 32)
    #pragma unroll
    for (int m = 8; m <= 32; m <<= 1) {
        a0 += __shfl_xor(a0, m); a1 += __shfl_xor(a1, m);
        a2 += __shfl_xor(a2, m); a3 += __shfl_xor(a3, m);
        a4 += __shfl_xor(a4, m); a5 += __shfl_xor(a5, m);
        a6 += __shfl_xor(a6, m); a7 += __shfl_xor(a7, m);
    }
    // groups 0/1 write the two float4 halves of the row
    if (g < 2) {
        float di = dis[node];
        uint4 u = ((const uint4*)(hsb + (size_t)node * C))[l];
        unsigned w0 = (g == 0) ? u.x : u.z;
        unsigned w1 = (g == 0) ? u.y : u.w;
        float s0 = bflo(w0), s1 = bfhi(w0), s2 = bflo(w1), s3 = bfhi(w1);
        float e0 = (g == 0) ? a0 : a4;
        float e1 = (g == 0) ? a1 : a5;
        float e2 = (g == 0) ? a2 : a6;
        float e3 = (g == 0) ? a3 : a7;
        float4 bv = ((const float4*)b)[l * 2 + g];
        float4 o;
        o.x = di * (s0 + e0) + bv.x;
        o.y = di * (s1 + e1) + bv.y;
        o.z = di * (s2 + e2) + bv.z;
        o.w = di * (s3 + e3) + bv.w;
        ((float4*)(out + (size_t)node * C))[l * 2 + g] = o;
    }
}

extern "C" void kernel_launch(void* const* d_in, const int* in_sizes, int n_in,
                              void* d_out, int out_size, void* d_ws, size_t ws_size,
                              hipStream_t stream) {
    const float* x   = (const float*)d_in[0];
    const int*   ei  = (const int*)d_in[1];   // [2, E]: src = ei[e], dst = ei[E+e]
    const float* W   = (const float*)d_in[2];
    const float* b   = (const float*)d_in[3];
    float*       out = (float*)d_out;

    const int N = in_sizes[0] / C;
    const int E = in_sizes[1] / 2;
    const int* src = ei;
    const int* dst = ei + E;

    // workspace layout (256B aligned slots)
    char* ws = (char*)d_ws;
    size_t o = 0;
    auto carve = [&](size_t bytes) { char* p = ws + o; o = (o + bytes + 255) & ~(size_t)255; return p; };
    unsigned* deg       = (unsigned*)carve((size_t)N * 4);
    unsigned* offs      = (unsigned*)carve((size_t)N * 4);
    unsigned* bsum      = (unsigned*)carve(1024 * 4);
    float*    dis       = (float*)carve((size_t)N * 4);
    unsigned* rank      = (unsigned*)carve((size_t)E * 4);
    unsigned* ssrc      = (unsigned*)carve((size_t)E * 4);
    unsigned short* hsb = (unsigned short*)carve((size_t)N * C * 2);

    // zero degree counters only
    hipMemsetAsync(deg, 0, (size_t)N * 4, stream);

    // degree histogram + per-edge rank
    count_deg_kernel<<<(E + 255) / 256, 256, 0, stream>>>(dst, deg, rank, E);

    // exclusive prefix sum of deg -> offs (+ fused dis)
    int nb = (N + 1023) / 1024;
    scan1_kernel<<<nb, 256, 0, stream>>>(deg, offs, bsum, dis, N);
    scan2_kernel<<<1, 256, 0, stream>>>(bsum, nb);

    // counting-sort edges by dst (atomic-free)
    bucket_kernel<<<(E + 255) / 256, 256, 0, stream>>>(src, dst, offs, bsum, rank, ssrc, E);

    // hs = dis * (x @ W), bf16
    gemm64_kernel<<<(N + 63) / 64, 256, 0, stream>>>(x, W, dis, hsb, N);

    // gather + self loop + bias
    gather_kernel<<<(N + 3) / 4, 256, 0, stream>>>(offs, bsum, deg, ssrc, dis, hsb, b, out, N);
}

// Round 9
// 130.960 us; speedup vs baseline: 1.2201x; 1.2201x over previous
//
#include <hip/hip_runtime.h>
#include <hip/hip_bf16.h>

#define C 64

// bf16 helpers (manual RNE pack / cheap unpack)
__device__ __forceinline__ float bflo(unsigned u) { return __uint_as_float(u << 16); }
__device__ __forceinline__ float bfhi(unsigned u) { return __uint_as_float(u & 0xffff0000u); }
__device__ __forceinline__ unsigned bfrne(float f) {
    unsigned u = __float_as_uint(f);
    return (u + 0x7fffu + ((u >> 16) & 1u)) >> 16;
}

// ---- count in-degree over dst; atomic return = rank of edge within its bucket ----
__global__ void count_deg_kernel(const int* __restrict__ dst, unsigned* __restrict__ deg,
                                 unsigned* __restrict__ rank, int E) {
    int e = blockIdx.x * blockDim.x + threadIdx.x;
    if (e < E) {
        rank[e] = atomicAdd(&deg[dst[e]], 1u);
    }
}

// ---- exclusive scan level 1 (1024/block) + dis = rsqrt(deg+1) fused ----
__global__ void scan1_kernel(const unsigned* __restrict__ deg, unsigned* __restrict__ offs,
                             unsigned* __restrict__ bsum, float* __restrict__ dis, int n) {
    __shared__ unsigned s[256];
    int t = threadIdx.x;
    int base = blockIdx.x * 1024 + t * 4;
    unsigned v0 = 0, v1 = 0, v2 = 0, v3 = 0;
    if (base + 0 < n) v0 = deg[base + 0];
    if (base + 1 < n) v1 = deg[base + 1];
    if (base + 2 < n) v2 = deg[base + 2];
    if (base + 3 < n) v3 = deg[base + 3];
    if (base + 0 < n) dis[base + 0] = rsqrtf((float)(v0 + 1u));
    if (base + 1 < n) dis[base + 1] = rsqrtf((float)(v1 + 1u));
    if (base + 2 < n) dis[base + 2] = rsqrtf((float)(v2 + 1u));
    if (base + 3 < n) dis[base + 3] = rsqrtf((float)(v3 + 1u));
    s[t] = v0 + v1 + v2 + v3;
    __syncthreads();
    for (int d = 1; d < 256; d <<= 1) {
        unsigned val = (t >= d) ? s[t - d] : 0u;
        __syncthreads();
        s[t] += val;
        __syncthreads();
    }
    unsigned excl = (t == 0) ? 0u : s[t - 1];
    if (t == 255) bsum[blockIdx.x] = s[255];
    if (base + 0 < n) offs[base + 0] = excl;
    if (base + 1 < n) offs[base + 1] = excl + v0;
    if (base + 2 < n) offs[base + 2] = excl + v0 + v1;
    if (base + 3 < n) offs[base + 3] = excl + v0 + v1 + v2;
}

// ---- scan block sums (single block; nb <= 256) ----
__global__ void scan2_kernel(unsigned* __restrict__ bsum, int nb) {
    __shared__ unsigned s[256];
    int t = threadIdx.x;
    s[t] = (t < nb) ? bsum[t] : 0u;
    __syncthreads();
    for (int d = 1; d < 256; d <<= 1) {
        unsigned val = (t >= d) ? s[t - d] : 0u;
        __syncthreads();
        s[t] += val;
        __syncthreads();
    }
    if (t < nb) bsum[t] = (t == 0) ? 0u : s[t - 1];
}

// ---- bucket edges by dst using precomputed rank (no atomics) ----
__global__ void bucket_kernel(const int* __restrict__ src, const int* __restrict__ dst,
                              const unsigned* __restrict__ offs, const unsigned* __restrict__ bsum,
                              const unsigned* __restrict__ rank, unsigned* __restrict__ ssrc, int E) {
    int e = blockIdx.x * blockDim.x + threadIdx.x;
    if (e < E) {
        int d = dst[e];
        unsigned pos = offs[d] + bsum[d >> 10] + rank[e];
        ssrc[pos] = (unsigned)src[e];
    }
}

// ---- hs(bf16) = dis[row] * (x @ W): LDS-tiled, 4x4 register micro-tile ----
// __launch_bounds__(256,4): cap 128 VGPRs. Round-8 build chose 232 VGPRs
// (full-unroll software pipelining) -> 8.9% occupancy, latency-bound, 58us.
// Body needs ~50 regs, so the cap binds without spilling. unroll 2 keeps
// the scheduler from re-inflating live ranges.
__global__ void __launch_bounds__(256, 4)
gemm64_kernel(const float* __restrict__ x, const float* __restrict__ W,
              const float* __restrict__ dis, unsigned short* __restrict__ hsb, int n) {
    __shared__ float Xl[64][68];
    __shared__ float Wl[64][64];
    int tid = threadIdx.x;
    int rbase = blockIdx.x * 64;
    for (int i = tid; i < 1024; i += 256) {
        ((float4*)Wl)[i] = ((const float4*)W)[i];
    }
    for (int i = tid; i < 1024; i += 256) {
        int r = i >> 4, kq = i & 15;
        float4 v;
        if (rbase + r < n) v = ((const float4*)(x + (size_t)(rbase + r) * C))[kq];
        else               v = make_float4(0.f, 0.f, 0.f, 0.f);
        *(float4*)&Xl[r][kq * 4] = v;
    }
    __syncthreads();

    int tx = tid & 15;      // channel group: channels 4tx..4tx+3
    int ty = tid >> 4;      // row group: rows 4ty..4ty+3
    float4 acc[4];
    #pragma unroll
    for (int j = 0; j < 4; ++j) acc[j] = make_float4(0.f, 0.f, 0.f, 0.f);

    #pragma unroll 2
    for (int kb = 0; kb < 16; ++kb) {
        float4 wv0 = *(const float4*)&Wl[kb * 4 + 0][tx * 4];
        float4 wv1 = *(const float4*)&Wl[kb * 4 + 1][tx * 4];
        float4 wv2 = *(const float4*)&Wl[kb * 4 + 2][tx * 4];
        float4 wv3 = *(const float4*)&Wl[kb * 4 + 3][tx * 4];
        #pragma unroll
        for (int j = 0; j < 4; ++j) {
            float4 xv = *(const float4*)&Xl[ty * 4 + j][kb * 4];
            acc[j].x = fmaf(xv.x, wv0.x, acc[j].x);
            acc[j].y = fmaf(xv.x, wv0.y, acc[j].y);
            acc[j].z = fmaf(xv.x, wv0.z, acc[j].z);
            acc[j].w = fmaf(xv.x, wv0.w, acc[j].w);
            acc[j].x = fmaf(xv.y, wv1.x, acc[j].x);
            acc[j].y = fmaf(xv.y, wv1.y, acc[j].y);
            acc[j].z = fmaf(xv.y, wv1.z, acc[j].z);
            acc[j].w = fmaf(xv.y, wv1.w, acc[j].w);
            acc[j].x = fmaf(xv.z, wv2.x, acc[j].x);
            acc[j].y = fmaf(xv.z, wv2.y, acc[j].y);
            acc[j].z = fmaf(xv.z, wv2.z, acc[j].z);
            acc[j].w = fmaf(xv.z, wv2.w, acc[j].w);
            acc[j].x = fmaf(xv.w, wv3.x, acc[j].x);
            acc[j].y = fmaf(xv.w, wv3.y, acc[j].y);
            acc[j].z = fmaf(xv.w, wv3.z, acc[j].z);
            acc[j].w = fmaf(xv.w, wv3.w, acc[j].w);
        }
    }
    #pragma unroll
    for (int j = 0; j < 4; ++j) {
        int row = rbase + ty * 4 + j;
        if (row < n) {
            float d = dis[row];
            unsigned p0 = bfrne(acc[j].x * d) | (bfrne(acc[j].y * d) << 16);
            unsigned p1 = bfrne(acc[j].z * d) | (bfrne(acc[j].w * d) << 16);
            ((uint2*)(hsb + (size_t)row * C))[tx] = make_uint2(p0, p1);
        }
    }
}

// ---- gather: one wave per node; 8 edge-groups x 8 lanes (uint4 = 8 bf16 each) ----
__global__ void gather_kernel(const unsigned* __restrict__ offs, const unsigned* __restrict__ bsum,
                              const unsigned* __restrict__ deg, const unsigned* __restrict__ ssrc,
                              const float* __restrict__ dis, const unsigned short* __restrict__ hsb,
                              const float* __restrict__ b, float* __restrict__ out, int n) {
    int node = blockIdx.x * 4 + (threadIdx.x >> 6);
    if (node >= n) return;
    int lane = threadIdx.x & 63;
    int g = lane >> 3;          // edge group 0..7
    int l = lane & 7;           // uint4 slot within 128B row (channels 8l..8l+7)
    unsigned off = offs[node] + bsum[node >> 10];
    unsigned dg  = deg[node];
    float a0 = 0.f, a1 = 0.f, a2 = 0.f, a3 = 0.f, a4 = 0.f, a5 = 0.f, a6 = 0.f, a7 = 0.f;
    unsigned k = 0;
    for (; k + 16 <= dg; k += 16) {
        unsigned s0 = ssrc[off + k + g];
        unsigned s1 = ssrc[off + k + 8 + g];
        uint4 v0 = ((const uint4*)(hsb + (size_t)s0 * C))[l];
        uint4 v1 = ((const uint4*)(hsb + (size_t)s1 * C))[l];
        a0 += bflo(v0.x) + bflo(v1.x); a1 += bfhi(v0.x) + bfhi(v1.x);
        a2 += bflo(v0.y) + bflo(v1.y); a3 += bfhi(v0.y) + bfhi(v1.y);
        a4 += bflo(v0.z) + bflo(v1.z); a5 += bfhi(v0.z) + bfhi(v1.z);
        a6 += bflo(v0.w) + bflo(v1.w); a7 += bfhi(v0.w) + bfhi(v1.w);
    }
    if (k + 8 <= dg) {
        unsigned s0 = ssrc[off + k + g];
        uint4 v0 = ((const uint4*)(hsb + (size_t)s0 * C))[l];
        a0 += bflo(v0.x); a1 += bfhi(v0.x);
        a2 += bflo(v0.y); a3 += bfhi(v0.y);
        a4 += bflo(v0.z); a5 += bfhi(v0.z);
        a6 += bflo(v0.w); a7 += bfhi(v0.w);
        k += 8;
    }
    if (k + g < dg) {
        unsigned s0 = ssrc[off + k + g];
        uint4 v0 = ((const uint4*)(hsb + (size_t)s0 * C))[l];
        a0 += bflo(v0.x); a1 += bfhi(v0.x);
        a2 += bflo(v0.y); a3 += bfhi(v0.y);
        a4 += bflo(v0.z); a5 += bfhi(v0.z);
        a6 += bflo(v0.w); a7 += bfhi(v0.w);
    }
    // reduce across the 8 edge groups (xor 8, 16, 32)
    #pragma unroll
    for (int m = 8; m <= 32; m <<= 1) {
        a0 += __shfl_xor(a0, m); a1 += __shfl_xor(a1, m);
        a2 += __shfl_xor(a2, m); a3 += __shfl_xor(a3, m);
        a4 += __shfl_xor(a4, m); a5 += __shfl_xor(a5, m);
        a6 += __shfl_xor(a6, m); a7 += __shfl_xor(a7, m);
    }
    // groups 0/1 write the two float4 halves of the row
    if (g < 2) {
        float di = dis[node];
        uint4 u = ((const uint4*)(hsb + (size_t)node * C))[l];
        unsigned w0 = (g == 0) ? u.x : u.z;
        unsigned w1 = (g == 0) ? u.y : u.w;
        float s0 = bflo(w0), s1 = bfhi(w0), s2 = bflo(w1), s3 = bfhi(w1);
        float e0 = (g == 0) ? a0 : a4;
        float e1 = (g == 0) ? a1 : a5;
        float e2 = (g == 0) ? a2 : a6;
        float e3 = (g == 0) ? a3 : a7;
        float4 bv = ((const float4*)b)[l * 2 + g];
        float4 o;
        o.x = di * (s0 + e0) + bv.x;
        o.y = di * (s1 + e1) + bv.y;
        o.z = di * (s2 + e2) + bv.z;
        o.w = di * (s3 + e3) + bv.w;
        ((float4*)(out + (size_t)node * C))[l * 2 + g] = o;
    }
}

extern "C" void kernel_launch(void* const* d_in, const int* in_sizes, int n_in,
                              void* d_out, int out_size, void* d_ws, size_t ws_size,
                              hipStream_t stream) {
    const float* x   = (const float*)d_in[0];
    const int*   ei  = (const int*)d_in[1];   // [2, E]: src = ei[e], dst = ei[E+e]
    const float* W   = (const float*)d_in[2];
    const float* b   = (const float*)d_in[3];
    float*       out = (float*)d_out;

    const int N = in_sizes[0] / C;
    const int E = in_sizes[1] / 2;
    const int* src = ei;
    const int* dst = ei + E;

    // workspace layout (256B aligned slots)
    char* ws = (char*)d_ws;
    size_t o = 0;
    auto carve = [&](size_t bytes) { char* p = ws + o; o = (o + bytes + 255) & ~(size_t)255; return p; };
    unsigned* deg       = (unsigned*)carve((size_t)N * 4);
    unsigned* offs      = (unsigned*)carve((size_t)N * 4);
    unsigned* bsum      = (unsigned*)carve(1024 * 4);
    float*    dis       = (float*)carve((size_t)N * 4);
    unsigned* rank      = (unsigned*)carve((size_t)E * 4);
    unsigned* ssrc      = (unsigned*)carve((size_t)E * 4);
    unsigned short* hsb = (unsigned short*)carve((size_t)N * C * 2);

    // zero degree counters only
    hipMemsetAsync(deg, 0, (size_t)N * 4, stream);

    // degree histogram + per-edge rank
    count_deg_kernel<<<(E + 255) / 256, 256, 0, stream>>>(dst, deg, rank, E);

    // exclusive prefix sum of deg -> offs (+ fused dis)
    int nb = (N + 1023) / 1024;
    scan1_kernel<<<nb, 256, 0, stream>>>(deg, offs, bsum, dis, N);
    scan2_kernel<<<1, 256, 0, stream>>>(bsum, nb);

    // counting-sort edges by dst (atomic-free)
    bucket_kernel<<<(E + 255) / 256, 256, 0, stream>>>(src, dst, offs, bsum, rank, ssrc, E);

    // hs = dis * (x @ W), bf16
    gemm64_kernel<<<(N + 63) / 64, 256, 0, stream>>>(x, W, dis, hsb, N);

    // gather + self loop + bias
    gather_kernel<<<(N + 3) / 4, 256, 0, stream>>>(offs, bsum, deg, ssrc, dis, hsb, b, out, N);
}

// Round 10
// 130.057 us; speedup vs baseline: 1.2285x; 1.0069x over previous
//
#include <hip/hip_runtime.h>
#include <hip/hip_bf16.h>

#define C 64

// bf16 helpers (manual RNE pack / cheap unpack)
__device__ __forceinline__ float bflo(unsigned u) { return __uint_as_float(u << 16); }
__device__ __forceinline__ float bfhi(unsigned u) { return __uint_as_float(u & 0xffff0000u); }
__device__ __forceinline__ unsigned bfrne(float f) {
    unsigned u = __float_as_uint(f);
    return (u + 0x7fffu + ((u >> 16) & 1u)) >> 16;
}

// ---- zero a u32 buffer (hipMemsetAsync's fillBufferAligned ran a tiny grid:
// 400KB took 44us at 9.4GB/s = single-CU store rate; this takes ~3us) ----
__global__ void zero_kernel(uint4* __restrict__ p, int n4) {
    int i = blockIdx.x * blockDim.x + threadIdx.x;
    if (i < n4) p[i] = make_uint4(0u, 0u, 0u, 0u);
}

// ---- count in-degree over dst; atomic return = rank of edge within its bucket ----
__global__ void count_deg_kernel(const int* __restrict__ dst, unsigned* __restrict__ deg,
                                 unsigned* __restrict__ rank, int E) {
    int e = blockIdx.x * blockDim.x + threadIdx.x;
    if (e < E) {
        rank[e] = atomicAdd(&deg[dst[e]], 1u);
    }
}

// ---- exclusive scan level 1 (1024/block) + dis = rsqrt(deg+1) fused ----
__global__ void scan1_kernel(const unsigned* __restrict__ deg, unsigned* __restrict__ offs,
                             unsigned* __restrict__ bsum, float* __restrict__ dis, int n) {
    __shared__ unsigned s[256];
    int t = threadIdx.x;
    int base = blockIdx.x * 1024 + t * 4;
    unsigned v0 = 0, v1 = 0, v2 = 0, v3 = 0;
    if (base + 0 < n) v0 = deg[base + 0];
    if (base + 1 < n) v1 = deg[base + 1];
    if (base + 2 < n) v2 = deg[base + 2];
    if (base + 3 < n) v3 = deg[base + 3];
    if (base + 0 < n) dis[base + 0] = rsqrtf((float)(v0 + 1u));
    if (base + 1 < n) dis[base + 1] = rsqrtf((float)(v1 + 1u));
    if (base + 2 < n) dis[base + 2] = rsqrtf((float)(v2 + 1u));
    if (base + 3 < n) dis[base + 3] = rsqrtf((float)(v3 + 1u));
    s[t] = v0 + v1 + v2 + v3;
    __syncthreads();
    for (int d = 1; d < 256; d <<= 1) {
        unsigned val = (t >= d) ? s[t - d] : 0u;
        __syncthreads();
        s[t] += val;
        __syncthreads();
    }
    unsigned excl = (t == 0) ? 0u : s[t - 1];
    if (t == 255) bsum[blockIdx.x] = s[255];
    if (base + 0 < n) offs[base + 0] = excl;
    if (base + 1 < n) offs[base + 1] = excl + v0;
    if (base + 2 < n) offs[base + 2] = excl + v0 + v1;
    if (base + 3 < n) offs[base + 3] = excl + v0 + v1 + v2;
}

// ---- scan block sums (single block; nb <= 256) ----
__global__ void scan2_kernel(unsigned* __restrict__ bsum, int nb) {
    __shared__ unsigned s[256];
    int t = threadIdx.x;
    s[t] = (t < nb) ? bsum[t] : 0u;
    __syncthreads();
    for (int d = 1; d < 256; d <<= 1) {
        unsigned val = (t >= d) ? s[t - d] : 0u;
        __syncthreads();
        s[t] += val;
        __syncthreads();
    }
    if (t < nb) bsum[t] = (t == 0) ? 0u : s[t - 1];
}

// ---- bucket edges by dst using precomputed rank (no atomics) ----
__global__ void bucket_kernel(const int* __restrict__ src, const int* __restrict__ dst,
                              const unsigned* __restrict__ offs, const unsigned* __restrict__ bsum,
                              const unsigned* __restrict__ rank, unsigned* __restrict__ ssrc, int E) {
    int e = blockIdx.x * blockDim.x + threadIdx.x;
    if (e < E) {
        int d = dst[e];
        unsigned pos = offs[d] + bsum[d >> 10] + rank[e];
        ssrc[pos] = (unsigned)src[e];
    }
}

// ---- hs(bf16) = dis[row] * (x @ W): LDS-tiled, 4x4 register micro-tile ----
// __launch_bounds__(256,4): cap 128 VGPRs (default build chose 232 -> 8.9%
// occupancy, latency-bound). unroll 2 keeps live ranges small.
__global__ void __launch_bounds__(256, 4)
gemm64_kernel(const float* __restrict__ x, const float* __restrict__ W,
              const float* __restrict__ dis, unsigned short* __restrict__ hsb, int n) {
    __shared__ float Xl[64][68];
    __shared__ float Wl[64][64];
    int tid = threadIdx.x;
    int rbase = blockIdx.x * 64;
    for (int i = tid; i < 1024; i += 256) {
        ((float4*)Wl)[i] = ((const float4*)W)[i];
    }
    for (int i = tid; i < 1024; i += 256) {
        int r = i >> 4, kq = i & 15;
        float4 v;
        if (rbase + r < n) v = ((const float4*)(x + (size_t)(rbase + r) * C))[kq];
        else               v = make_float4(0.f, 0.f, 0.f, 0.f);
        *(float4*)&Xl[r][kq * 4] = v;
    }
    __syncthreads();

    int tx = tid & 15;      // channel group: channels 4tx..4tx+3
    int ty = tid >> 4;      // row group: rows 4ty..4ty+3
    float4 acc[4];
    #pragma unroll
    for (int j = 0; j < 4; ++j) acc[j] = make_float4(0.f, 0.f, 0.f, 0.f);

    #pragma unroll 2
    for (int kb = 0; kb < 16; ++kb) {
        float4 wv0 = *(const float4*)&Wl[kb * 4 + 0][tx * 4];
        float4 wv1 = *(const float4*)&Wl[kb * 4 + 1][tx * 4];
        float4 wv2 = *(const float4*)&Wl[kb * 4 + 2][tx * 4];
        float4 wv3 = *(const float4*)&Wl[kb * 4 + 3][tx * 4];
        #pragma unroll
        for (int j = 0; j < 4; ++j) {
            float4 xv = *(const float4*)&Xl[ty * 4 + j][kb * 4];
            acc[j].x = fmaf(xv.x, wv0.x, acc[j].x);
            acc[j].y = fmaf(xv.x, wv0.y, acc[j].y);
            acc[j].z = fmaf(xv.x, wv0.z, acc[j].z);
            acc[j].w = fmaf(xv.x, wv0.w, acc[j].w);
            acc[j].x = fmaf(xv.y, wv1.x, acc[j].x);
            acc[j].y = fmaf(xv.y, wv1.y, acc[j].y);
            acc[j].z = fmaf(xv.y, wv1.z, acc[j].z);
            acc[j].w = fmaf(xv.y, wv1.w, acc[j].w);
            acc[j].x = fmaf(xv.z, wv2.x, acc[j].x);
            acc[j].y = fmaf(xv.z, wv2.y, acc[j].y);
            acc[j].z = fmaf(xv.z, wv2.z, acc[j].z);
            acc[j].w = fmaf(xv.z, wv2.w, acc[j].w);
            acc[j].x = fmaf(xv.w, wv3.x, acc[j].x);
            acc[j].y = fmaf(xv.w, wv3.y, acc[j].y);
            acc[j].z = fmaf(xv.w, wv3.z, acc[j].z);
            acc[j].w = fmaf(xv.w, wv3.w, acc[j].w);
        }
    }
    #pragma unroll
    for (int j = 0; j < 4; ++j) {
        int row = rbase + ty * 4 + j;
        if (row < n) {
            float d = dis[row];
            unsigned p0 = bfrne(acc[j].x * d) | (bfrne(acc[j].y * d) << 16);
            unsigned p1 = bfrne(acc[j].z * d) | (bfrne(acc[j].w * d) << 16);
            ((uint2*)(hsb + (size_t)row * C))[tx] = make_uint2(p0, p1);
        }
    }
}

// ---- gather: one wave per node; 8 edge-groups x 8 lanes (uint4 = 8 bf16 each) ----
__global__ void gather_kernel(const unsigned* __restrict__ offs, const unsigned* __restrict__ bsum,
                              const unsigned* __restrict__ deg, const unsigned* __restrict__ ssrc,
                              const float* __restrict__ dis, const unsigned short* __restrict__ hsb,
                              const float* __restrict__ b, float* __restrict__ out, int n) {
    int node = blockIdx.x * 4 + (threadIdx.x >> 6);
    if (node >= n) return;
    int lane = threadIdx.x & 63;
    int g = lane >> 3;          // edge group 0..7
    int l = lane & 7;           // uint4 slot within 128B row (channels 8l..8l+7)
    unsigned off = offs[node] + bsum[node >> 10];
    unsigned dg  = deg[node];
    float a0 = 0.f, a1 = 0.f, a2 = 0.f, a3 = 0.f, a4 = 0.f, a5 = 0.f, a6 = 0.f, a7 = 0.f;
    unsigned k = 0;
    for (; k + 16 <= dg; k += 16) {
        unsigned s0 = ssrc[off + k + g];
        unsigned s1 = ssrc[off + k + 8 + g];
        uint4 v0 = ((const uint4*)(hsb + (size_t)s0 * C))[l];
        uint4 v1 = ((const uint4*)(hsb + (size_t)s1 * C))[l];
        a0 += bflo(v0.x) + bflo(v1.x); a1 += bfhi(v0.x) + bfhi(v1.x);
        a2 += bflo(v0.y) + bflo(v1.y); a3 += bfhi(v0.y) + bfhi(v1.y);
        a4 += bflo(v0.z) + bflo(v1.z); a5 += bfhi(v0.z) + bfhi(v1.z);
        a6 += bflo(v0.w) + bflo(v1.w); a7 += bfhi(v0.w) + bfhi(v1.w);
    }
    if (k + 8 <= dg) {
        unsigned s0 = ssrc[off + k + g];
        uint4 v0 = ((const uint4*)(hsb + (size_t)s0 * C))[l];
        a0 += bflo(v0.x); a1 += bfhi(v0.x);
        a2 += bflo(v0.y); a3 += bfhi(v0.y);
        a4 += bflo(v0.z); a5 += bfhi(v0.z);
        a6 += bflo(v0.w); a7 += bfhi(v0.w);
        k += 8;
    }
    if (k + g < dg) {
        unsigned s0 = ssrc[off + k + g];
        uint4 v0 = ((const uint4*)(hsb + (size_t)s0 * C))[l];
        a0 += bflo(v0.x); a1 += bfhi(v0.x);
        a2 += bflo(v0.y); a3 += bfhi(v0.y);
        a4 += bflo(v0.z); a5 += bfhi(v0.z);
        a6 += bflo(v0.w); a7 += bfhi(v0.w);
    }
    // reduce across the 8 edge groups (xor 8, 16, 32)
    #pragma unroll
    for (int m = 8; m <= 32; m <<= 1) {
        a0 += __shfl_xor(a0, m); a1 += __shfl_xor(a1, m);
        a2 += __shfl_xor(a2, m); a3 += __shfl_xor(a3, m);
        a4 += __shfl_xor(a4, m); a5 += __shfl_xor(a5, m);
        a6 += __shfl_xor(a6, m); a7 += __shfl_xor(a7, m);
    }
    // groups 0/1 write the two float4 halves of the row
    if (g < 2) {
        float di = dis[node];
        uint4 u = ((const uint4*)(hsb + (size_t)node * C))[l];
        unsigned w0 = (g == 0) ? u.x : u.z;
        unsigned w1 = (g == 0) ? u.y : u.w;
        float s0 = bflo(w0), s1 = bfhi(w0), s2 = bflo(w1), s3 = bfhi(w1);
        float e0 = (g == 0) ? a0 : a4;
        float e1 = (g == 0) ? a1 : a5;
        float e2 = (g == 0) ? a2 : a6;
        float e3 = (g == 0) ? a3 : a7;
        float4 bv = ((const float4*)b)[l * 2 + g];
        float4 o;
        o.x = di * (s0 + e0) + bv.x;
        o.y = di * (s1 + e1) + bv.y;
        o.z = di * (s2 + e2) + bv.z;
        o.w = di * (s3 + e3) + bv.w;
        ((float4*)(out + (size_t)node * C))[l * 2 + g] = o;
    }
}

extern "C" void kernel_launch(void* const* d_in, const int* in_sizes, int n_in,
                              void* d_out, int out_size, void* d_ws, size_t ws_size,
                              hipStream_t stream) {
    const float* x   = (const float*)d_in[0];
    const int*   ei  = (const int*)d_in[1];   // [2, E]: src = ei[e], dst = ei[E+e]
    const float* W   = (const float*)d_in[2];
    const float* b   = (const float*)d_in[3];
    float*       out = (float*)d_out;

    const int N = in_sizes[0] / C;
    const int E = in_sizes[1] / 2;
    const int* src = ei;
    const int* dst = ei + E;

    // workspace layout (256B aligned slots)
    char* ws = (char*)d_ws;
    size_t o = 0;
    auto carve = [&](size_t bytes) { char* p = ws + o; o = (o + bytes + 255) & ~(size_t)255; return p; };
    unsigned* deg       = (unsigned*)carve((size_t)N * 4);
    unsigned* offs      = (unsigned*)carve((size_t)N * 4);
    unsigned* bsum      = (unsigned*)carve(1024 * 4);
    float*    dis       = (float*)carve((size_t)N * 4);
    unsigned* rank      = (unsigned*)carve((size_t)E * 4);
    unsigned* ssrc      = (unsigned*)carve((size_t)E * 4);
    unsigned short* hsb = (unsigned short*)carve((size_t)N * C * 2);

    // zero degree counters with a proper grid (hipMemsetAsync = 1-WG fill, 44us)
    int n4 = (N + 3) / 4;                       // deg is carve-padded, safe to round up
    zero_kernel<<<(n4 + 255) / 256, 256, 0, stream>>>((uint4*)deg, n4);

    // degree histogram + per-edge rank
    count_deg_kernel<<<(E + 255) / 256, 256, 0, stream>>>(dst, deg, rank, E);

    // exclusive prefix sum of deg -> offs (+ fused dis)
    int nb = (N + 1023) / 1024;
    scan1_kernel<<<nb, 256, 0, stream>>>(deg, offs, bsum, dis, N);
    scan2_kernel<<<1, 256, 0, stream>>>(bsum, nb);

    // counting-sort edges by dst (atomic-free)
    bucket_kernel<<<(E + 255) / 256, 256, 0, stream>>>(src, dst, offs, bsum, rank, ssrc, E);

    // hs = dis * (x @ W), bf16
    gemm64_kernel<<<(N + 63) / 64, 256, 0, stream>>>(x, W, dis, hsb, N);

    // gather + self loop + bias
    gather_kernel<<<(N + 3) / 4, 256, 0, stream>>>(offs, bsum, deg, ssrc, dis, hsb, b, out, N);
}